// Round 1
// baseline (523.162 us; speedup 1.0000x reference)
//
#include <hip/hip_runtime.h>

// LSTMModel: 4-layer LSTM (H=50, IN=7, B=1024, T=512) + FC(50->25 relu ->1).
// R9 = R8 (474us) + recurrent/input phase split with skew-2 software pipeline.
//
// Theory: R8's per-tick [MFMA -> update -> barrier] serializes the matrix and
// VALU pipes (MfmaUtil 39% + VALUBusy 54% ~= 96% of the tick: 2107cy ~= MFMA
// 883cy + VALU 1138cy back-to-back, barrier-locksteps all 16 waves into the
// same phase). Each LSTM step's gate GEMM = input-half (W_ih*h_{l-1}, K-groups
// g0,g1: independent of the layer's own recurrence) + recurrent-half
// (W_hh*h_l(t-1), K-groups g2,g3). With layer skew 2 (layer l does timestep t
// at slot s = t + 2l), the input-half for t+1 runs in slot s AFTER update(t),
// carrying the partial accumulator across the barrier in registers. The
// update's VALU chain then overlaps the input-half MFMAs (same basic block:
// update math is branchless, only the LDS stores are lane-predicated), and the
// MFMA/VALU phase mix across waves breaks the lockstep convoy.
// Parity algebra is UNCHANGED (every buffer written in slot s to [(s+1)&1],
// read in slot s+1 from [s&1]) -- h_{l-1}(t+1) is written in slot s-1 and read
// by layer l's input phase in slot s. Slots: 515 -> 518 (skew 6 not 3).
// L0 keeps single-phase (x(t) is packed into g0; it's the light layer).
//
// Xpack[2][4][80]: row = [x(t) 0..6 | 1.0 at 7 | h0(t-1) at 8..57].
// Xstage[64][4][8]: raw-x ring, refilled 32 steps/burst every 32 ticks.
// Hbuf[3][2][4][80]: own-h of L1..L3; const-1.0 at slot 56 (bias for L2/L3
// input view; multiplies A=0 in the own view).

#define H 50
#define INSZ 7
#define TT 512
#define NL 4
#define FC1N 25
#define BPG 4
#define NBLK 256
#define NTHREADS 1024
#define HS 80        // row stride in halves (40 dw = 8 mod 32: <=2-way, free)
#define BIASL 56

typedef _Float16 half_t;
typedef __attribute__((ext_vector_type(8))) _Float16 half8_t;
typedef __attribute__((ext_vector_type(4))) float float4_t;

struct Params {
  const float* x;
  const float* Wih[NL];
  const float* Whh[NL];
  const float* bih[NL];
  const float* bhh[NL];
  const float* W1;
  const float* b1;
  const float* W2;
  const float* b2;
  float* out;
};

#define MFMA16(A, B, C) __builtin_amdgcn_mfma_f32_16x16x32_f16((A), (B), (C), 0, 0, 0)
#define EXP2F(x) __builtin_amdgcn_exp2f(x)
#define RCPF(x) __builtin_amdgcn_rcpf(x)

__global__ __launch_bounds__(NTHREADS, 4) void lstm_r9(Params p) {
  __shared__ __align__(16) half_t Xpack[2][BPG][HS];     // L0 B-row / L1 input
  __shared__ __align__(16) half_t Hbuf[3][2][BPG][HS];   // own-h L1..L3
  __shared__ __align__(16) half_t Xstage[64][BPG][8];    // raw-x ring
  __shared__ float fc_h[BPG][H];
  __shared__ float fc1_buf[BPG][FC1N];

  const int tid = threadIdx.x;
  const int b0 = blockIdx.x * BPG;
  const int lane = tid & 63;
  const int quad = lane >> 4;
  const int col = lane & 15;
  const int glay = tid >> 8;                     // layer (4 waves each)
  const int wl = (((tid >> 6) & 3) + glay) & 3;  // M-chunk, SIMD-balanced

  // ---- A fragments: row r = wl*64 + t4*16 + col (unit-major r=4u+q),
  //      k = g*32 + quad*8 + j.
  half8_t afrag[4][4];
#pragma unroll
  for (int t4 = 0; t4 < 4; ++t4) {
#pragma unroll
    for (int g = 0; g < 4; ++g) {
      half8_t v;
#pragma unroll
      for (int j = 0; j < 8; ++j) {
        const int r = wl * 64 + t4 * 16 + col;
        const int u = r >> 2, q = r & 3;
        const int k = g * 32 + quad * 8 + j;
        float wv = 0.0f;
        if (u < H) {
          const int row = q * H + u;
          if (glay == 0) {           // K=64: x 0..6, bias 7, own-h 8..57
            if (k < INSZ) wv = p.Wih[0][row * INSZ + k];
            else if (k == 7) wv = p.bih[0][row] + p.bhh[0][row];
            else if (k >= 8 && k < 8 + H) wv = p.Whh[0][row * H + (k - 8)];
          } else if (glay == 1) {    // input from Xpack: bias 7, in-h 8..57
            if (k == 7) wv = p.bih[1][row] + p.bhh[1][row];
            else if (k >= 8 && k < 8 + H) wv = p.Wih[1][row * H + (k - 8)];
            else if (k >= 64 && k < 64 + H) wv = p.Whh[1][row * H + (k - 64)];
          } else {                   // in-h 0..49, bias 56, own-h 64..113
            if (k < H) wv = p.Wih[glay][row * H + k];
            else if (k == BIASL) wv = p.bih[glay][row] + p.bhh[glay][row];
            else if (k >= 64 && k < 64 + H) wv = p.Whh[glay][row * H + (k - 64)];
          }
        }
        v[j] = (half_t)wv;
      }
      afrag[t4][g] = v;
    }
  }

  // ---- init LDS ----
  {
    unsigned* xz = (unsigned*)Xpack;
    for (int i = tid; i < 2 * BPG * HS / 2; i += NTHREADS) xz[i] = 0u;
    unsigned* hz = (unsigned*)Hbuf;
    for (int i = tid; i < 3 * 2 * BPG * HS / 2; i += NTHREADS) hz[i] = 0u;
  }
  __syncthreads();
  if (tid < 8) {  // Xpack bias-1.0 at slot 7, both parities
    Xpack[tid >> 2][tid & 3][7] = (half_t)1.0f;
  } else if (tid < 8 + 24) {  // Hbuf const-1.0 at slot 56
    const int i = tid - 8, l = i >> 3, pr = (i >> 2) & 1, b = i & 3;
    Hbuf[l][pr][b][BIASL] = (half_t)1.0f;
  }
  // ring fill t=0..63 + x(0) into Xpack[0]
  for (int i = tid; i < 64 * BPG * INSZ; i += NTHREADS) {
    const int t = i / (BPG * INSZ), rem = i % (BPG * INSZ);
    const int b = rem / INSZ, k = rem % INSZ;
    const half_t xh = (half_t)p.x[((size_t)(b0 + b) * TT + t) * INSZ + k];
    Xstage[t][b][k] = xh;
    if (t == 0) Xpack[0][b][k] = xh;
  }
  __syncthreads();

  // ---- per-lane roles ----
  const int bb = col & 3;
  const int tsel = col >> 2;
  const int uu = 16 * wl + 4 * tsel + quad;
  const bool updact = (uu < H);

  // phase-hoisted pointers: read [s&1], store [(s+1)&1].
  const half_t* pin2[2];
  const half_t* pown2[2];
  half_t* pst2[2];
  if (glay == 0) {
    pin2[0] = &Xpack[0][bb][quad * 8];
    pin2[1] = &Xpack[1][bb][quad * 8];
    pown2[0] = pin2[0];  // unused
    pown2[1] = pin2[1];
    pst2[0] = &Xpack[1][bb][8 + uu];
    pst2[1] = &Xpack[0][bb][8 + uu];
  } else if (glay == 1) {
    pin2[0] = &Xpack[0][bb][quad * 8];
    pin2[1] = &Xpack[1][bb][quad * 8];
    pown2[0] = &Hbuf[0][0][bb][quad * 8];
    pown2[1] = &Hbuf[0][1][bb][quad * 8];
    pst2[0] = &Hbuf[0][1][bb][uu];
    pst2[1] = &Hbuf[0][0][bb][uu];
  } else {
    pin2[0] = &Hbuf[glay - 2][0][bb][quad * 8];
    pin2[1] = &Hbuf[glay - 2][1][bb][quad * 8];
    pown2[0] = &Hbuf[glay - 1][0][bb][quad * 8];
    pown2[1] = &Hbuf[glay - 1][1][bb][quad * 8];
    pst2[0] = &Hbuf[glay - 1][1][bb][uu];
    pst2[1] = &Hbuf[glay - 1][0][bb][uu];
  }
  const half_t* in_e = pin2[0];
  const half_t* in_o = pin2[1];
  const half_t* own_e = pown2[0];
  const half_t* own_o = pown2[1];
  half_t* st_e = pst2[0];
  half_t* st_o = pst2[1];

  // x-copy + ring-refill role: layer-0 wl==3 wave (lightest: 2 MFMAs)
  const bool xwave = (glay == 0) && (wl == 3);
  const bool xcopy = xwave && (lane < BPG * INSZ);
  const int cb = lane / INSZ, ck = lane % INSZ;  // valid when xcopy
  const int rb = lane >> 5;                      // refill: batch pair
  const int rt = lane & 31;                      //         t offset

  float cst = 0.0f;
  const float4_t fzc = {0.0f, 0.0f, 0.0f, 0.0f};
  // Carried partial accumulators (glay>=1): input-half of NEXT timestep,
  // filled in slot s, completed+consumed in slot s+1.
  float4_t c0 = fzc, c1 = fzc, c2 = fzc, c3 = fzc;

  // Branchless update math; only the LDS stores are lane-predicated (slot 56
  // of Hbuf rows holds the const-1.0 bias -- garbage lanes must not store).
#define UPDATE(A0, A1, A2, A3, PST, FCW)                                        \
  {                                                                             \
    const float4_t g01 = (col & 4) ? (A1) : (A0);                               \
    const float4_t g23 = (col & 4) ? (A3) : (A2);                               \
    const float4_t ga = (col & 8) ? g23 : g01;                                  \
    const float di = 1.0f + EXP2F(-1.442695041f * ga[0]);                       \
    const float df = 1.0f + EXP2F(-1.442695041f * ga[1]);                       \
    const float dg = 1.0f + EXP2F(-2.885390082f * ga[2]);                       \
    const float dq = 1.0f + EXP2F(-1.442695041f * ga[3]);                       \
    const float r1 = RCPF(di * df);                                             \
    const float r2 = RCPF(dg * dq);                                             \
    const float gi = r1 * df;                                                   \
    const float gf = r1 * di;                                                   \
    const float gg = 2.0f * (r2 * dq) - 1.0f;                                   \
    const float go = r2 * dg;                                                   \
    cst = gf * cst + gi * gg;                                                   \
    const float dc = 1.0f + EXP2F(-2.885390082f * cst);                         \
    const float h = go * (2.0f * RCPF(dc) - 1.0f);                              \
    if (updact) {                                                               \
      *(PST) = (half_t)h;                                                       \
      if (FCW) fc_h[bb][uu] = h;                                                \
    }                                                                           \
  }

  // L0: single-phase (x+bias+own-h all in g0,g1), fresh acc each slot.
#define SLOT_L0(PIN, PST, FCW)                                                  \
  {                                                                             \
    const half8_t v0 = *(const half8_t*)(PIN);                                  \
    const half8_t v1 = *(const half8_t*)((PIN) + 32);                           \
    if (wl != 3) {                                                              \
      float4_t a0 = fzc, a1 = fzc, a2 = fzc, a3 = fzc;                          \
      a0 = MFMA16(afrag[0][0], v0, a0); a1 = MFMA16(afrag[1][0], v0, a1);       \
      a2 = MFMA16(afrag[2][0], v0, a2); a3 = MFMA16(afrag[3][0], v0, a3);       \
      a0 = MFMA16(afrag[0][1], v1, a0); a1 = MFMA16(afrag[1][1], v1, a1);       \
      a2 = MFMA16(afrag[2][1], v1, a2); a3 = MFMA16(afrag[3][1], v1, a3);       \
      UPDATE(a0, a1, a2, a3, PST, FCW)                                          \
    } else {                                                                    \
      float4_t a0 = fzc;                                                        \
      a0 = MFMA16(afrag[0][0], v0, a0);                                         \
      a0 = MFMA16(afrag[0][1], v1, a0);                                         \
      UPDATE(a0, a0, a0, a0, PST, FCW)                                          \
    }                                                                           \
  }

  // L1..L3 steady slot: own-half MFMAs complete the carried acc -> update(t)
  // -> input-half MFMAs for t+1 refill the acc (independent of the update
  // chain; same basic block so the scheduler overlaps them with the VALU).
#define SLOT_LX(PIN, POWN, PST, FCW)                                            \
  {                                                                             \
    const half8_t v2 = *(const half8_t*)(POWN);                                 \
    const half8_t v3 = *(const half8_t*)((POWN) + 32);                          \
    const half8_t u0 = *(const half8_t*)(PIN);                                  \
    const half8_t u1 = *(const half8_t*)((PIN) + 32);                           \
    if (wl != 3) {                                                              \
      c0 = MFMA16(afrag[0][2], v2, c0); c1 = MFMA16(afrag[1][2], v2, c1);       \
      c2 = MFMA16(afrag[2][2], v2, c2); c3 = MFMA16(afrag[3][2], v2, c3);       \
      c0 = MFMA16(afrag[0][3], v3, c0); c1 = MFMA16(afrag[1][3], v3, c1);       \
      c2 = MFMA16(afrag[2][3], v3, c2); c3 = MFMA16(afrag[3][3], v3, c3);       \
      UPDATE(c0, c1, c2, c3, PST, FCW)                                          \
      c0 = MFMA16(afrag[0][0], u0, fzc); c1 = MFMA16(afrag[1][0], u0, fzc);     \
      c2 = MFMA16(afrag[2][0], u0, fzc); c3 = MFMA16(afrag[3][0], u0, fzc);     \
      c0 = MFMA16(afrag[0][1], u1, c0); c1 = MFMA16(afrag[1][1], u1, c1);       \
      c2 = MFMA16(afrag[2][1], u1, c2); c3 = MFMA16(afrag[3][1], u1, c3);       \
    } else {                                                                    \
      c0 = MFMA16(afrag[0][2], v2, c0);                                         \
      c0 = MFMA16(afrag[0][3], v3, c0);                                         \
      UPDATE(c0, c0, c0, c0, PST, FCW)                                          \
      c0 = MFMA16(afrag[0][0], u0, fzc);                                        \
      c0 = MFMA16(afrag[0][1], u1, c0);                                         \
    }                                                                           \
  }

  // Guarded (prologue/tail) variant: own+update and input phases separately
  // gated by slot-uniform conditions.
#define SLOT_LX_G(PIN, POWN, PST, DOOWN, DOIN, FCW)                             \
  {                                                                             \
    if (wl != 3) {                                                              \
      if (DOOWN) {                                                              \
        const half8_t v2 = *(const half8_t*)(POWN);                             \
        const half8_t v3 = *(const half8_t*)((POWN) + 32);                      \
        c0 = MFMA16(afrag[0][2], v2, c0); c1 = MFMA16(afrag[1][2], v2, c1);     \
        c2 = MFMA16(afrag[2][2], v2, c2); c3 = MFMA16(afrag[3][2], v2, c3);     \
        c0 = MFMA16(afrag[0][3], v3, c0); c1 = MFMA16(afrag[1][3], v3, c1);     \
        c2 = MFMA16(afrag[2][3], v3, c2); c3 = MFMA16(afrag[3][3], v3, c3);     \
        UPDATE(c0, c1, c2, c3, PST, FCW)                                        \
      }                                                                         \
      if (DOIN) {                                                               \
        const half8_t u0 = *(const half8_t*)(PIN);                              \
        const half8_t u1 = *(const half8_t*)((PIN) + 32);                       \
        c0 = MFMA16(afrag[0][0], u0, fzc); c1 = MFMA16(afrag[1][0], u0, fzc);   \
        c2 = MFMA16(afrag[2][0], u0, fzc); c3 = MFMA16(afrag[3][0], u0, fzc);   \
        c0 = MFMA16(afrag[0][1], u1, c0); c1 = MFMA16(afrag[1][1], u1, c1);     \
        c2 = MFMA16(afrag[2][1], u1, c2); c3 = MFMA16(afrag[3][1], u1, c3);     \
      }                                                                         \
    } else {                                                                    \
      if (DOOWN) {                                                              \
        const half8_t v2 = *(const half8_t*)(POWN);                             \
        const half8_t v3 = *(const half8_t*)((POWN) + 32);                      \
        c0 = MFMA16(afrag[0][2], v2, c0);                                       \
        c0 = MFMA16(afrag[0][3], v3, c0);                                       \
        UPDATE(c0, c0, c0, c0, PST, FCW)                                        \
      }                                                                         \
      if (DOIN) {                                                               \
        const half8_t u0 = *(const half8_t*)(PIN);                              \
        const half8_t u1 = *(const half8_t*)((PIN) + 32);                       \
        c0 = MFMA16(afrag[0][0], u0, fzc);                                      \
        c0 = MFMA16(afrag[0][1], u1, c0);                                       \
      }                                                                         \
    }                                                                           \
  }

  // x-copy: ring row (s+1) -> Xpack[(s+1)&1] slots 0..6 (one light wave)
#define XCOPY(S)                                                                \
  if (xcopy) {                                                                  \
    const int tn = (S) + 1;                                                     \
    Xpack[tn & 1][cb][ck] = Xstage[tn & 63][cb][ck];                            \
  }

  // ---- prologue: s = 0..5 (guarded, dynamic parity) ----
  // Layer l: own+update active from s=2l (t=s-2l), input-half from s=2l-1.
  for (int s = 0; s < 6; ++s) {
    const int ph = s & 1;
    if (glay == 0) {
      SLOT_L0(pin2[ph], pst2[ph], false)
    } else {
      SLOT_LX_G(pin2[ph], pown2[ph], pst2[ph], s >= 2 * glay, s >= 2 * glay - 1,
                false)
    }
    XCOPY(s)
    __syncthreads();
  }

  // ---- steady: s = 6..511, all phases active, unrolled x2, even-first ----
  for (int s = 6; s < 512; s += 2) {
    {  // even slot s (ph=0)
      if (xwave && (s & 31) == 8 && s < 480) {  // ring refill burst
        const int tb = (s & ~31) + 32;
#pragma unroll
        for (int pp = 0; pp < 2; ++pp) {
          const int b = rb + 2 * pp;
          const int t = tb + rt;
          const float* src = &p.x[((size_t)(b0 + b) * TT + t) * INSZ];
          half_t* dst = &Xstage[t & 63][b][0];
#pragma unroll
          for (int k = 0; k < INSZ; ++k) dst[k] = (half_t)src[k];
        }
      }
      if (glay == 0) {
        SLOT_L0(in_e, st_e, false)
      } else {
        SLOT_LX(in_e, own_e, st_e, false)
      }
      XCOPY(s)
    }
    __syncthreads();
    {  // odd slot s+1 (ph=1)
      if (glay == 0) {
        SLOT_L0(in_o, st_o, false)
      } else {
        SLOT_LX(in_o, own_o, st_o, false)
      }
      XCOPY(s + 1)
    }
    __syncthreads();
  }

  // ---- tail: s = 512..517 (guarded; no x-copy; L0 inactive) ----
  for (int s = 512; s < TT + 2 * (NL - 1); ++s) {
    const int ph = s & 1;
    if (glay > 0) {
      const int t = s - 2 * glay;
      const bool fcw = (glay == NL - 1) && (t == TT - 1);
      SLOT_LX_G(pin2[ph], pown2[ph], pst2[ph], t < TT, t + 1 < TT, fcw)
    }
    __syncthreads();
  }

  // ---- FC head (fp32) ----
  if (tid < BPG * FC1N) {
    const int b = tid / FC1N, j = tid % FC1N;
    const float* w = p.W1 + j * H;
    float a = p.b1[j];
#pragma unroll
    for (int k = 0; k < H; ++k) a += fc_h[b][k] * w[k];
    fc1_buf[b][j] = fmaxf(a, 0.0f);
  }
  __syncthreads();
  if (tid < BPG) {
    float a = p.b2[0];
#pragma unroll
    for (int j = 0; j < FC1N; ++j) a += fc1_buf[tid][j] * p.W2[j];
    p.out[b0 + tid] = a;
  }
}

extern "C" void kernel_launch(void* const* d_in, const int* in_sizes, int n_in,
                              void* d_out, int out_size, void* d_ws, size_t ws_size,
                              hipStream_t stream) {
  Params p;
  p.x = (const float*)d_in[0];
  for (int l = 0; l < NL; ++l) {
    p.Wih[l] = (const float*)d_in[1 + 4 * l];
    p.Whh[l] = (const float*)d_in[2 + 4 * l];
    p.bih[l] = (const float*)d_in[3 + 4 * l];
    p.bhh[l] = (const float*)d_in[4 + 4 * l];
  }
  p.W1 = (const float*)d_in[17];
  p.b1 = (const float*)d_in[18];
  p.W2 = (const float*)d_in[19];
  p.b2 = (const float*)d_in[20];
  p.out = (float*)d_out;

  hipLaunchKernelGGL(lstm_r9, dim3(NBLK), dim3(NTHREADS), 0, stream, p);
}

// Round 2
// 478.049 us; speedup vs baseline: 1.0944x; 1.0944x over previous
//
#include <hip/hip_runtime.h>

// LSTMModel: 4-layer LSTM (H=50, IN=7, B=1024, T=512) + FC(50->25 relu ->1).
// R10 = R8 (474us, reverted from R9's failed phase-split) + VALU work cuts.
//
// R9 post-mortem: splitting the gate GEMM across the barrier DROPPED both
// MfmaUtil (38.8->34.5) and VALUBusy (54->45) and grew idle 7%->20%: in-order
// issue means the per-wave stream still serializes, and carried accumulators
// added AGPR churn + a longer issue tail into each barrier. R8's cross-wave
// stagger (4 waves/SIMD free-running between barriers) already was the
// overlap; with pipes summing to ~93% of the tick, the lever is REMOVING
// work, not rescheduling it. Changes vs R8:
//  1. exp2 scale constants folded into the A-fragment rows: row r=4u+q is
//     pre-scaled by -1.442695 (i,f,o gates) or -2.885390 (g gate), bias
//     included, so the update computes di = 1+exp2(ga) directly: -4 v_mul
//     per update lane per tick (800 lanes/CU-tick).
//  2. zero-C MFMA start: first MFMA of each chain consumes a persistent
//     zero float4 as C instead of read-modify on a freshly zeroed acc
//     (kills per-tick v_accvgpr_write zero-init if the compiler emitted it).
//  3. s_setprio(1) around the MFMA cluster (T5): waves here have real role
//     diversity per barrier window (staggered phases, light xwave) -- the
//     regime where setprio measured +4-7%.
//
// Xpack[2][4][80]: row = [x(t) 0..6 | 1.0 at 7 | h0(t-1) at 8..57].
// Xstage[64][4][8]: raw-x ring, refilled 32 steps/burst every 32 ticks.
// Hbuf[3][2][4][80]: own-h of L1..L3; const-1.0 at slot 56 (bias for L2/L3
// input view; multiplies A=0 in the own view).

#define H 50
#define INSZ 7
#define TT 512
#define NL 4
#define FC1N 25
#define BPG 4
#define NBLK 256
#define NTHREADS 1024
#define HS 80        // row stride in halves (40 dw = 8 mod 32: <=2-way, free)
#define BIASL 56

typedef _Float16 half_t;
typedef __attribute__((ext_vector_type(8))) _Float16 half8_t;
typedef __attribute__((ext_vector_type(4))) float float4_t;

struct Params {
  const float* x;
  const float* Wih[NL];
  const float* Whh[NL];
  const float* bih[NL];
  const float* bhh[NL];
  const float* W1;
  const float* b1;
  const float* W2;
  const float* b2;
  float* out;
};

#define MFMA16(A, B, C) __builtin_amdgcn_mfma_f32_16x16x32_f16((A), (B), (C), 0, 0, 0)
#define EXP2F(x) __builtin_amdgcn_exp2f(x)
#define RCPF(x) __builtin_amdgcn_rcpf(x)

__global__ __launch_bounds__(NTHREADS, 4) void lstm_r10(Params p) {
  __shared__ __align__(16) half_t Xpack[2][BPG][HS];     // L0 B-row / L1 input
  __shared__ __align__(16) half_t Hbuf[3][2][BPG][HS];   // own-h L1..L3
  __shared__ __align__(16) half_t Xstage[64][BPG][8];    // raw-x ring
  __shared__ float fc_h[BPG][H];
  __shared__ float fc1_buf[BPG][FC1N];

  const int tid = threadIdx.x;
  const int b0 = blockIdx.x * BPG;
  const int lane = tid & 63;
  const int quad = lane >> 4;
  const int col = lane & 15;
  const int glay = tid >> 8;                     // layer (4 waves each)
  const int wl = (((tid >> 6) & 3) + glay) & 3;  // M-chunk, SIMD-balanced

  // ---- A fragments: row r = wl*64 + t4*16 + col (unit-major r=4u+q),
  //      k = g*32 + quad*8 + j. Rows pre-scaled by the gate's exp2 constant
  //      (q==2 -> tanh arg -2.885390, else sigmoid arg -1.442695), bias
  //      included, so UPDATE skips the per-gate multiply.
  half8_t afrag[4][4];
#pragma unroll
  for (int t4 = 0; t4 < 4; ++t4) {
#pragma unroll
    for (int g = 0; g < 4; ++g) {
      half8_t v;
#pragma unroll
      for (int j = 0; j < 8; ++j) {
        const int r = wl * 64 + t4 * 16 + col;
        const int u = r >> 2, q = r & 3;
        const int k = g * 32 + quad * 8 + j;
        float wv = 0.0f;
        if (u < H) {
          const int row = q * H + u;
          if (glay == 0) {           // K=64: x 0..6, bias 7, own-h 8..57
            if (k < INSZ) wv = p.Wih[0][row * INSZ + k];
            else if (k == 7) wv = p.bih[0][row] + p.bhh[0][row];
            else if (k >= 8 && k < 8 + H) wv = p.Whh[0][row * H + (k - 8)];
          } else if (glay == 1) {    // input from Xpack: bias 7, in-h 8..57
            if (k == 7) wv = p.bih[1][row] + p.bhh[1][row];
            else if (k >= 8 && k < 8 + H) wv = p.Wih[1][row * H + (k - 8)];
            else if (k >= 64 && k < 64 + H) wv = p.Whh[1][row * H + (k - 64)];
          } else {                   // in-h 0..49, bias 56, own-h 64..113
            if (k < H) wv = p.Wih[glay][row * H + k];
            else if (k == BIASL) wv = p.bih[glay][row] + p.bhh[glay][row];
            else if (k >= 64 && k < 64 + H) wv = p.Whh[glay][row * H + (k - 64)];
          }
          wv *= (q == 2) ? -2.885390082f : -1.442695041f;  // fold exp2 scale
        }
        v[j] = (half_t)wv;
      }
      afrag[t4][g] = v;
    }
  }

  // ---- init LDS ----
  {
    unsigned* xz = (unsigned*)Xpack;
    for (int i = tid; i < 2 * BPG * HS / 2; i += NTHREADS) xz[i] = 0u;
    unsigned* hz = (unsigned*)Hbuf;
    for (int i = tid; i < 3 * 2 * BPG * HS / 2; i += NTHREADS) hz[i] = 0u;
  }
  __syncthreads();
  if (tid < 8) {  // Xpack bias-1.0 at slot 7, both parities
    Xpack[tid >> 2][tid & 3][7] = (half_t)1.0f;
  } else if (tid < 8 + 24) {  // Hbuf const-1.0 at slot 56
    const int i = tid - 8, l = i >> 3, pr = (i >> 2) & 1, b = i & 3;
    Hbuf[l][pr][b][BIASL] = (half_t)1.0f;
  }
  // ring fill t=0..63 + x(0) into Xpack[0]
  for (int i = tid; i < 64 * BPG * INSZ; i += NTHREADS) {
    const int t = i / (BPG * INSZ), rem = i % (BPG * INSZ);
    const int b = rem / INSZ, k = rem % INSZ;
    const half_t xh = (half_t)p.x[((size_t)(b0 + b) * TT + t) * INSZ + k];
    Xstage[t][b][k] = xh;
    if (t == 0) Xpack[0][b][k] = xh;
  }
  __syncthreads();

  // ---- per-lane roles ----
  const int bb = col & 3;
  const int tsel = col >> 2;
  const int uu = 16 * wl + 4 * tsel + quad;
  const bool updact = (uu < H);

  // phase-hoisted pointers: read [s&1], store [(s+1)&1].
  const half_t* pin2[2];
  const half_t* pown2[2];
  half_t* pst2[2];
  if (glay == 0) {
    pin2[0] = &Xpack[0][bb][quad * 8];
    pin2[1] = &Xpack[1][bb][quad * 8];
    pown2[0] = pin2[0];  // unused
    pown2[1] = pin2[1];
    pst2[0] = &Xpack[1][bb][8 + uu];
    pst2[1] = &Xpack[0][bb][8 + uu];
  } else if (glay == 1) {
    pin2[0] = &Xpack[0][bb][quad * 8];
    pin2[1] = &Xpack[1][bb][quad * 8];
    pown2[0] = &Hbuf[0][0][bb][quad * 8];
    pown2[1] = &Hbuf[0][1][bb][quad * 8];
    pst2[0] = &Hbuf[0][1][bb][uu];
    pst2[1] = &Hbuf[0][0][bb][uu];
  } else {
    pin2[0] = &Hbuf[glay - 2][0][bb][quad * 8];
    pin2[1] = &Hbuf[glay - 2][1][bb][quad * 8];
    pown2[0] = &Hbuf[glay - 1][0][bb][quad * 8];
    pown2[1] = &Hbuf[glay - 1][1][bb][quad * 8];
    pst2[0] = &Hbuf[glay - 1][1][bb][uu];
    pst2[1] = &Hbuf[glay - 1][0][bb][uu];
  }
  const half_t* in_e = pin2[0];
  const half_t* in_o = pin2[1];
  const half_t* own_e = pown2[0];
  const half_t* own_o = pown2[1];
  half_t* st_e = pst2[0];
  half_t* st_o = pst2[1];

  // x-copy + ring-refill role: layer-0 wl==3 wave (lightest: 2 MFMAs)
  const bool xwave = (glay == 0) && (wl == 3);
  const bool xcopy = xwave && (lane < BPG * INSZ);
  const int cb = lane / INSZ, ck = lane % INSZ;  // valid when xcopy
  const int rb = lane >> 5;                      // refill: batch pair
  const int rt = lane & 31;                      //         t offset

  float cst = 0.0f;
  const float4_t fzc = {0.0f, 0.0f, 0.0f, 0.0f};

#define TICK_BODY(PIN, POWN, PST, FCW)                                          \
  {                                                                             \
    float4_t a0, a1, a2, a3;                                                    \
    if (glay == 0) {                                                            \
      const half8_t v0 = *(const half8_t*)(PIN);                                \
      const half8_t v1 = *(const half8_t*)((PIN) + 32);                         \
      __builtin_amdgcn_s_setprio(1);                                            \
      if (wl != 3) {                                                            \
        a0 = MFMA16(afrag[0][0], v0, fzc); a1 = MFMA16(afrag[1][0], v0, fzc);   \
        a2 = MFMA16(afrag[2][0], v0, fzc); a3 = MFMA16(afrag[3][0], v0, fzc);   \
        a0 = MFMA16(afrag[0][1], v1, a0); a1 = MFMA16(afrag[1][1], v1, a1);     \
        a2 = MFMA16(afrag[2][1], v1, a2); a3 = MFMA16(afrag[3][1], v1, a3);     \
      } else {                                                                  \
        a0 = MFMA16(afrag[0][0], v0, fzc);                                      \
        a0 = MFMA16(afrag[0][1], v1, a0);                                       \
        a1 = a0; a2 = a0; a3 = a0;                                              \
      }                                                                         \
      __builtin_amdgcn_s_setprio(0);                                            \
    } else {                                                                    \
      const half8_t v0 = *(const half8_t*)(PIN);                                \
      const half8_t v1 = *(const half8_t*)((PIN) + 32);                         \
      const half8_t v2 = *(const half8_t*)(POWN);                               \
      const half8_t v3 = *(const half8_t*)((POWN) + 32);                        \
      __builtin_amdgcn_s_setprio(1);                                            \
      if (wl != 3) {                                                            \
        a0 = MFMA16(afrag[0][0], v0, fzc); a1 = MFMA16(afrag[1][0], v0, fzc);   \
        a2 = MFMA16(afrag[2][0], v0, fzc); a3 = MFMA16(afrag[3][0], v0, fzc);   \
        a0 = MFMA16(afrag[0][1], v1, a0); a1 = MFMA16(afrag[1][1], v1, a1);     \
        a2 = MFMA16(afrag[2][1], v1, a2); a3 = MFMA16(afrag[3][1], v1, a3);     \
        a0 = MFMA16(afrag[0][2], v2, a0); a1 = MFMA16(afrag[1][2], v2, a1);     \
        a2 = MFMA16(afrag[2][2], v2, a2); a3 = MFMA16(afrag[3][2], v2, a3);     \
        a0 = MFMA16(afrag[0][3], v3, a0); a1 = MFMA16(afrag[1][3], v3, a1);     \
        a2 = MFMA16(afrag[2][3], v3, a2); a3 = MFMA16(afrag[3][3], v3, a3);     \
      } else {                                                                  \
        a0 = MFMA16(afrag[0][0], v0, fzc);                                      \
        a0 = MFMA16(afrag[0][1], v1, a0);                                       \
        a0 = MFMA16(afrag[0][2], v2, a0);                                       \
        a0 = MFMA16(afrag[0][3], v3, a0);                                       \
        a1 = a0; a2 = a0; a3 = a0;                                              \
      }                                                                         \
      __builtin_amdgcn_s_setprio(0);                                            \
    }                                                                           \
    if (updact) {                                                               \
      const float4_t g01 = (col & 4) ? a1 : a0;                                 \
      const float4_t g23 = (col & 4) ? a3 : a2;                                 \
      const float4_t ga = (col & 8) ? g23 : g01;                                \
      const float di = 1.0f + EXP2F(ga[0]);                                     \
      const float df = 1.0f + EXP2F(ga[1]);                                     \
      const float dg = 1.0f + EXP2F(ga[2]);                                     \
      const float dq = 1.0f + EXP2F(ga[3]);                                     \
      const float r1 = RCPF(di * df);                                           \
      const float r2 = RCPF(dg * dq);                                           \
      const float gi = r1 * df;                                                 \
      const float gf = r1 * di;                                                 \
      const float gg = 2.0f * (r2 * dq) - 1.0f;                                 \
      const float go = r2 * dg;                                                 \
      cst = gf * cst + gi * gg;                                                 \
      const float dc = 1.0f + EXP2F(-2.885390082f * cst);                       \
      const float h = go * (2.0f * RCPF(dc) - 1.0f);                            \
      *(PST) = (half_t)h;                                                       \
      if (FCW) fc_h[bb][uu] = h;                                                \
    }                                                                           \
  }

  // x-copy: ring row (s+1) -> Xpack[(s+1)&1] slots 0..6 (one light wave)
#define XCOPY(S)                                                                \
  if (xcopy) {                                                                  \
    const int tn = (S) + 1;                                                     \
    Xpack[tn & 1][cb][ck] = Xstage[tn & 63][cb][ck];                            \
  }

  // ---- prologue: s = 0..2 (guarded, dynamic parity) ----
  for (int s = 0; s < 3; ++s) {
    const int t = s - glay;
    if (t >= 0) {
      const int ph = s & 1;
      TICK_BODY(pin2[ph], pown2[ph], pst2[ph], false)
    }
    XCOPY(s)
    __syncthreads();
  }

  // ---- steady: s = 3..510, unrolled x2, compile-time phase ----
  for (int s = 3; s < 511; s += 2) {
    {  // odd tick s (ph=1)
      TICK_BODY(in_o, own_o, st_o, false)
      XCOPY(s)
    }
    __syncthreads();
    {  // even tick s+1 (ph=0)
      const int s2 = s + 1;
      if (xwave && (s2 & 31) == 8 && s2 < 480) {  // ring refill burst
        const int tb = (s2 & ~31) + 32;
#pragma unroll
        for (int pp = 0; pp < 2; ++pp) {
          const int b = rb + 2 * pp;
          const int t = tb + rt;
          const float* src = &p.x[((size_t)(b0 + b) * TT + t) * INSZ];
          half_t* dst = &Xstage[t & 63][b][0];
#pragma unroll
          for (int k = 0; k < INSZ; ++k) dst[k] = (half_t)src[k];
        }
      }
      TICK_BODY(in_e, own_e, st_e, false)
      XCOPY(s2)
    }
    __syncthreads();
  }

  // ---- tail: s = 511..514 (guarded; no x-copy) ----
  for (int s = 511; s < TT + NL - 1; ++s) {
    const int t = s - glay;
    if (t < TT) {
      const int ph = s & 1;
      const bool fcw = (glay == NL - 1) && (t == TT - 1);
      TICK_BODY(pin2[ph], pown2[ph], pst2[ph], fcw)
    }
    __syncthreads();
  }

  // ---- FC head (fp32) ----
  if (tid < BPG * FC1N) {
    const int b = tid / FC1N, j = tid % FC1N;
    const float* w = p.W1 + j * H;
    float a = p.b1[j];
#pragma unroll
    for (int k = 0; k < H; ++k) a += fc_h[b][k] * w[k];
    fc1_buf[b][j] = fmaxf(a, 0.0f);
  }
  __syncthreads();
  if (tid < BPG) {
    float a = p.b2[0];
#pragma unroll
    for (int j = 0; j < FC1N; ++j) a += fc1_buf[tid][j] * p.W2[j];
    p.out[b0 + tid] = a;
  }
}

extern "C" void kernel_launch(void* const* d_in, const int* in_sizes, int n_in,
                              void* d_out, int out_size, void* d_ws, size_t ws_size,
                              hipStream_t stream) {
  Params p;
  p.x = (const float*)d_in[0];
  for (int l = 0; l < NL; ++l) {
    p.Wih[l] = (const float*)d_in[1 + 4 * l];
    p.Whh[l] = (const float*)d_in[2 + 4 * l];
    p.bih[l] = (const float*)d_in[3 + 4 * l];
    p.bhh[l] = (const float*)d_in[4 + 4 * l];
  }
  p.W1 = (const float*)d_in[17];
  p.b1 = (const float*)d_in[18];
  p.W2 = (const float*)d_in[19];
  p.b2 = (const float*)d_in[20];
  p.out = (float*)d_out;

  hipLaunchKernelGGL(lstm_r10, dim3(NBLK), dim3(NTHREADS), 0, stream, p);
}